// Round 4
// baseline (320.323 us; speedup 1.0000x reference)
//
#include <hip/hip_runtime.h>
#include <float.h>

// Problem constants (from reference setup_inputs)
#define NS   16384   // samples
#define K1   512     // d_in
#define F    256     // n_feat
#define NC   1000    // n_classes
#define NCP  1024    // padded classes
#define SPB  16      // samples per block
#define NTHR 256
#define KC   64      // phase-1 K chunk
#define NSL  (F / 4) // 64 phase-2 k-slices of 4

// NOTE on numerics: preds = feats / max(||feats||,eps) divides each row by a
// positive scalar => argmax(preds@means.T) == argmax(feats@means.T). We skip
// the normalization. Tie-break: reference argmin takes FIRST min => lowest
// class index wins (strict > per-lane ascending + min-index merges).

// -------- prep: means4[s][c][0..3] = means[c][4s+k], zero-pad c>=NC --------
__global__ void prep_means(const float* __restrict__ means,
                           float* __restrict__ means4) {
    int t = blockIdx.x * blockDim.x + threadIdx.x;  // 65536 threads (s,c)
    int s = t >> 10;        // 0..63
    int c = t & 1023;       // 0..1023
    float4 v = make_float4(0.f, 0.f, 0.f, 0.f);
    if (c < NC) v = *reinterpret_cast<const float4*>(means + (size_t)c * F + s * 4);
    *reinterpret_cast<float4*>(means4 + ((size_t)s * NCP + c) * 4) = v;
}

// 4 blocks/CU (16 waves/CU): LDS ~25 KB, VGPR capped at 128 by launch_bounds.
__launch_bounds__(NTHR, 4)
__global__ void fused_cls_kernel(const float* __restrict__ x,
                                 const float* __restrict__ W,
                                 const float* __restrict__ means4,
                                 float* __restrict__ out) {
    __shared__ __align__(16) float xs2[2][SPB][KC + 4];  // 8704 B, phase-1 ping-pong
    __shared__ __align__(16) float feats[SPB][F];        // 16384 B, persistent
    __shared__ float cand_v[SPB][4];
    __shared__ int   cand_i[SPB][4];
    __shared__ int   bidx[SPB];

    const int tid = threadIdx.x;
    const int s0  = blockIdx.x * SPB;

    // ================= Phase 1: feats = x[s0:s0+16, :] @ W =================
    {
        const int tn = tid & 31;       // 32 column groups (8 cols each)
        const int ts = tid >> 5;       // 8 sample groups (2 samples each)
        const int n0 = tn * 8;
        const int xrow = tid >> 4;     // staging: row 0..15
        const int xc   = (tid & 15) * 4;

        float acc1[2][8];
#pragma unroll
        for (int i = 0; i < 2; ++i)
#pragma unroll
            for (int n = 0; n < 8; ++n) acc1[i][n] = 0.f;

        // preload chunk 0: one float4 per thread
        float4 xr = *reinterpret_cast<const float4*>(
            x + (size_t)(s0 + xrow) * K1 + xc);

        for (int kc8 = 0; kc8 < K1 / KC; ++kc8) {
            float (*xs)[KC + 4] = xs2[kc8 & 1];
            *reinterpret_cast<float4*>(&xs[xrow][xc]) = xr;
            __syncthreads();   // single barrier per chunk (ping-pong)
            if (kc8 + 1 < K1 / KC)
                xr = *reinterpret_cast<const float4*>(
                    x + (size_t)(s0 + xrow) * K1 + (kc8 + 1) * KC + xc);

            const int kc = kc8 * KC;
#pragma unroll 4
            for (int k4 = 0; k4 < KC / 4; ++k4) {
                float a[2][4];
#pragma unroll
                for (int i = 0; i < 2; ++i) {
                    float4 t = *reinterpret_cast<const float4*>(&xs[ts * 2 + i][k4 * 4]);
                    a[i][0] = t.x; a[i][1] = t.y; a[i][2] = t.z; a[i][3] = t.w;
                }
                float4 bw[4][2];
#pragma unroll
                for (int j = 0; j < 4; ++j) {
                    const float* wp = W + (size_t)(kc + k4 * 4 + j) * F + n0;
                    bw[j][0] = *reinterpret_cast<const float4*>(wp);
                    bw[j][1] = *reinterpret_cast<const float4*>(wp + 4);
                }
#pragma unroll
                for (int j = 0; j < 4; ++j) {
#pragma unroll
                    for (int i = 0; i < 2; ++i) {
                        float av = a[i][j];
                        acc1[i][0] += av * bw[j][0].x;
                        acc1[i][1] += av * bw[j][0].y;
                        acc1[i][2] += av * bw[j][0].z;
                        acc1[i][3] += av * bw[j][0].w;
                        acc1[i][4] += av * bw[j][1].x;
                        acc1[i][5] += av * bw[j][1].y;
                        acc1[i][6] += av * bw[j][1].z;
                        acc1[i][7] += av * bw[j][1].w;
                    }
                }
            }
            // no trailing barrier: next iter writes the OTHER buffer; the next
            // barrier orders re-use of this one.
        }

        // park feats in LDS (never goes to HBM)
#pragma unroll
        for (int i = 0; i < 2; ++i) {
            *reinterpret_cast<float4*>(&feats[ts * 2 + i][n0])     =
                make_float4(acc1[i][0], acc1[i][1], acc1[i][2], acc1[i][3]);
            *reinterpret_cast<float4*>(&feats[ts * 2 + i][n0 + 4]) =
                make_float4(acc1[i][4], acc1[i][5], acc1[i][6], acc1[i][7]);
        }
        __syncthreads();
    }

    // ===== Phase 2: scores = feats @ means.T — barrier-free, L2-streamed =====
    // Wave tr owns class range [tr*256, tr*256+256) for ALL 16 samples.
    // Lane tc owns classes cb + tc + 64*j, j=0..3 (ascending => tie-break safe).
    const int tc = tid & 63;
    const int tr = tid >> 6;
    const int cb = tr * 256;

    float acc[SPB][4];   // 64 persistent accumulators
#pragma unroll
    for (int i = 0; i < SPB; ++i)
#pragma unroll
        for (int j = 0; j < 4; ++j) acc[i][j] = 0.f;

    // slice-s data for this wave: contiguous 1KB per j, coalesced, L2-hot
    float4 bv[4];
#pragma unroll
    for (int j = 0; j < 4; ++j)
        bv[j] = *reinterpret_cast<const float4*>(
            means4 + ((size_t)0 * NCP + cb + tc + 64 * j) * 4);

    for (int s = 0; s < NSL; ++s) {
        float4 bn[4];
        const int sn = (s + 1 < NSL) ? s + 1 : s;   // clamped prefetch
#pragma unroll
        for (int j = 0; j < 4; ++j)
            bn[j] = *reinterpret_cast<const float4*>(
                means4 + ((size_t)sn * NCP + cb + tc + 64 * j) * 4);

#pragma unroll
        for (int i = 0; i < SPB; ++i) {
            float4 av = *reinterpret_cast<const float4*>(&feats[i][s * 4]);  // broadcast
#pragma unroll
            for (int j = 0; j < 4; ++j) {
                acc[i][j] += av.x * bv[j].x;
                acc[i][j] += av.y * bv[j].y;
                acc[i][j] += av.z * bv[j].z;
                acc[i][j] += av.w * bv[j].w;
            }
        }
#pragma unroll
        for (int j = 0; j < 4; ++j) bv[j] = bn[j];
    }

    // ---- argmax: lane-local (j ascending) -> 64-lane butterfly -> cross-wave ----
#pragma unroll
    for (int i = 0; i < SPB; ++i) {
        float v  = -FLT_MAX;
        int   ix = 0x7FFFFFFF;
#pragma unroll
        for (int j = 0; j < 4; ++j) {
            int c = cb + tc + 64 * j;
            if (c < NC) {
                float sc = acc[i][j];
                if (sc > v) { v = sc; ix = c; }   // strict >: lowest class wins
            }
        }
#pragma unroll
        for (int off = 1; off < 64; off <<= 1) {
            float ov = __shfl_xor(v, off, 64);
            int   oi = __shfl_xor(ix, off, 64);
            if (ov > v || (ov == v && oi < ix)) { v = ov; ix = oi; }
        }
        if (tc == i) { cand_v[i][tr] = v; cand_i[i][tr] = ix; }
    }
    __syncthreads();

    if (tid < SPB) {
        float v  = cand_v[tid][0];
        int   ix = cand_i[tid][0];
#pragma unroll
        for (int r = 1; r < 4; ++r) {
            float ov = cand_v[tid][r];
            int   oi = cand_i[tid][r];
            if (ov > v || (ov == v && oi < ix)) { v = ov; ix = oi; }
        }
        bidx[tid] = ix;
    }
    __syncthreads();

    // ================= Epilogue: write one-hot rows =================
    const int NF4 = NC / 4;  // 250 float4 per row
    for (int q = tid; q < SPB * NF4; q += NTHR) {
        int row   = q / NF4;
        int c4    = q - row * NF4;
        int b     = bidx[row];
        int cbase = c4 * 4;
        float4 v;
        v.x = (cbase + 0 == b) ? 1.f : 0.f;
        v.y = (cbase + 1 == b) ? 1.f : 0.f;
        v.z = (cbase + 2 == b) ? 1.f : 0.f;
        v.w = (cbase + 3 == b) ? 1.f : 0.f;
        *reinterpret_cast<float4*>(out + (size_t)(s0 + row) * NC + cbase) = v;
    }
}

extern "C" void kernel_launch(void* const* d_in, const int* in_sizes, int n_in,
                              void* d_out, int out_size, void* d_ws, size_t ws_size,
                              hipStream_t stream) {
    const float* x     = (const float*)d_in[0];
    const float* W     = (const float*)d_in[1];
    const float* means = (const float*)d_in[2];
    float* out         = (float*)d_out;
    float* means4      = (float*)d_ws;   // 64*1024*4 floats = 1 MB

    prep_means<<<(64 * NCP) / NTHR, NTHR, 0, stream>>>(means, means4);
    fused_cls_kernel<<<NS / SPB, NTHR, 0, stream>>>(x, W, means4, out);
}

// Round 5
// 304.455 us; speedup vs baseline: 1.0521x; 1.0521x over previous
//
#include <hip/hip_runtime.h>
#include <float.h>

// Problem constants (from reference setup_inputs)
#define NS   16384   // samples
#define K1   512     // d_in
#define F    256     // n_feat
#define NC   1000    // n_classes
#define NCP  1024    // padded classes
#define SPB  16      // samples per block
#define NTHR 256
#define KC   64      // phase-1 K chunk
#define NSL  (F / 4) // 64 phase-2 k-slices of 4

// NOTE on numerics: preds = feats / max(||feats||,eps) divides each row by a
// positive scalar => argmax(preds@means.T) == argmax(feats@means.T). We skip
// the normalization. Tie-break: reference argmin takes FIRST min => lowest
// class index wins (strict > per-lane ascending + min-index merges).

// -------- prep: means4[s][c][0..3] = means[c][4s+k], zero-pad c>=NC --------
__global__ void prep_means(const float* __restrict__ means,
                           float* __restrict__ means4) {
    int t = blockIdx.x * blockDim.x + threadIdx.x;  // 65536 threads (s,c)
    int s = t >> 10;        // 0..63
    int c = t & 1023;       // 0..1023
    float4 v = make_float4(0.f, 0.f, 0.f, 0.f);
    if (c < NC) v = *reinterpret_cast<const float4*>(means + (size_t)c * F + s * 4);
    *reinterpret_cast<float4*>(means4 + ((size_t)s * NCP + c) * 4) = v;
}

// Pin waves/EU to exactly 4 => VGPR budget 128. Round 4's launch_bounds(256,4)
// let the backend squeeze to 64 VGPR (8-wave tier) and SPILL the 64-wide
// accumulator (WRITE_SIZE +24MB of scratch). min=max=4 prevents that.
__attribute__((amdgpu_flat_work_group_size(NTHR, NTHR), amdgpu_waves_per_eu(4, 4)))
__global__ void fused_cls_kernel(const float* __restrict__ x,
                                 const float* __restrict__ W,
                                 const float* __restrict__ means4,
                                 float* __restrict__ out) {
    __shared__ __align__(16) float xs2[2][SPB][KC + 4];  // 8704 B, phase-1 ping-pong
    __shared__ __align__(16) float feats[SPB][F];        // 16384 B, persistent
    __shared__ float cand_v[SPB][4];
    __shared__ int   cand_i[SPB][4];
    __shared__ int   bidx[SPB];

    const int tid = threadIdx.x;
    const int s0  = blockIdx.x * SPB;

    // ================= Phase 1: feats = x[s0:s0+16, :] @ W =================
    {
        const int tn = tid & 31;       // 32 column groups (8 cols each)
        const int ts = tid >> 5;       // 8 sample groups (2 samples each)
        const int n0 = tn * 8;
        const int xrow = tid >> 4;     // staging: row 0..15
        const int xc   = (tid & 15) * 4;

        float acc1[2][8];
#pragma unroll
        for (int i = 0; i < 2; ++i)
#pragma unroll
            for (int n = 0; n < 8; ++n) acc1[i][n] = 0.f;

        // preload chunk 0: one float4 per thread
        float4 xr = *reinterpret_cast<const float4*>(
            x + (size_t)(s0 + xrow) * K1 + xc);

        for (int kc8 = 0; kc8 < K1 / KC; ++kc8) {
            float (*xs)[KC + 4] = xs2[kc8 & 1];
            *reinterpret_cast<float4*>(&xs[xrow][xc]) = xr;
            __syncthreads();   // single barrier per chunk (ping-pong)
            if (kc8 + 1 < K1 / KC)
                xr = *reinterpret_cast<const float4*>(
                    x + (size_t)(s0 + xrow) * K1 + (kc8 + 1) * KC + xc);

            const int kc = kc8 * KC;
#pragma unroll 4
            for (int k4 = 0; k4 < KC / 4; ++k4) {
                float a[2][4];
#pragma unroll
                for (int i = 0; i < 2; ++i) {
                    float4 t = *reinterpret_cast<const float4*>(&xs[ts * 2 + i][k4 * 4]);
                    a[i][0] = t.x; a[i][1] = t.y; a[i][2] = t.z; a[i][3] = t.w;
                }
                float4 bw[4][2];
#pragma unroll
                for (int j = 0; j < 4; ++j) {
                    const float* wp = W + (size_t)(kc + k4 * 4 + j) * F + n0;
                    bw[j][0] = *reinterpret_cast<const float4*>(wp);
                    bw[j][1] = *reinterpret_cast<const float4*>(wp + 4);
                }
#pragma unroll
                for (int j = 0; j < 4; ++j) {
#pragma unroll
                    for (int i = 0; i < 2; ++i) {
                        float av = a[i][j];
                        acc1[i][0] += av * bw[j][0].x;
                        acc1[i][1] += av * bw[j][0].y;
                        acc1[i][2] += av * bw[j][0].z;
                        acc1[i][3] += av * bw[j][0].w;
                        acc1[i][4] += av * bw[j][1].x;
                        acc1[i][5] += av * bw[j][1].y;
                        acc1[i][6] += av * bw[j][1].z;
                        acc1[i][7] += av * bw[j][1].w;
                    }
                }
            }
            // no trailing barrier: next iter writes the OTHER buffer; the next
            // barrier orders re-use of this one.
        }

        // park feats in LDS (never goes to HBM)
#pragma unroll
        for (int i = 0; i < 2; ++i) {
            *reinterpret_cast<float4*>(&feats[ts * 2 + i][n0])     =
                make_float4(acc1[i][0], acc1[i][1], acc1[i][2], acc1[i][3]);
            *reinterpret_cast<float4*>(&feats[ts * 2 + i][n0 + 4]) =
                make_float4(acc1[i][4], acc1[i][5], acc1[i][6], acc1[i][7]);
        }
        __syncthreads();
    }

    // ===== Phase 2: scores = feats @ means.T — barrier-free, L2-streamed =====
    // Wave tr owns class range [tr*256, tr*256+256) for ALL 16 samples.
    // Lane tc owns classes cb + tc + 64*j, j=0..3 (ascending => tie-break safe).
    const int tc = tid & 63;
    const int tr = tid >> 6;
    const int cb = tr * 256;

    float acc[SPB][4];   // 64 persistent accumulators
#pragma unroll
    for (int i = 0; i < SPB; ++i)
#pragma unroll
        for (int j = 0; j < 4; ++j) acc[i][j] = 0.f;

    // per-lane streaming pointer; the 4 j-loads use immediate offsets
    // (64*j*16B = 0..3072, fits 13-bit signed) and mp advances by a constant.
    const float* mp = means4 + (size_t)(cb + tc) * 4;
    const float* fp = &feats[0][0];

    float4 bv[4];
#pragma unroll
    for (int j = 0; j < 4; ++j)
        bv[j] = *reinterpret_cast<const float4*>(mp + j * 64 * 4);
    mp += NCP * 4;

    for (int s = 0; s < NSL; ++s) {
        float4 bn[4];
#pragma unroll
        for (int j = 0; j < 4; ++j)
            bn[j] = *reinterpret_cast<const float4*>(mp + j * 64 * 4);  // prefetch s+1
        mp += NCP * 4;   // one harmless over-advance on the last iter (no deref)

#pragma unroll
        for (int i = 0; i < SPB; ++i) {
            // broadcast read (whole wave same addr): ds offset imm = i*1024
            float4 av = *reinterpret_cast<const float4*>(fp + i * F);
#pragma unroll
            for (int j = 0; j < 4; ++j) {
                acc[i][j] += av.x * bv[j].x;
                acc[i][j] += av.y * bv[j].y;
                acc[i][j] += av.z * bv[j].z;
                acc[i][j] += av.w * bv[j].w;
            }
        }
        fp += 4;
#pragma unroll
        for (int j = 0; j < 4; ++j) bv[j] = bn[j];
    }

    // ---- argmax: lane-local (j ascending) -> 64-lane butterfly -> cross-wave ----
#pragma unroll
    for (int i = 0; i < SPB; ++i) {
        float v  = -FLT_MAX;
        int   ix = 0x7FFFFFFF;
#pragma unroll
        for (int j = 0; j < 4; ++j) {
            int c = cb + tc + 64 * j;
            if (c < NC) {
                float sc = acc[i][j];
                if (sc > v) { v = sc; ix = c; }   // strict >: lowest class wins
            }
        }
#pragma unroll
        for (int off = 1; off < 64; off <<= 1) {
            float ov = __shfl_xor(v, off, 64);
            int   oi = __shfl_xor(ix, off, 64);
            if (ov > v || (ov == v && oi < ix)) { v = ov; ix = oi; }
        }
        if (tc == i) { cand_v[i][tr] = v; cand_i[i][tr] = ix; }
    }
    __syncthreads();

    if (tid < SPB) {
        float v  = cand_v[tid][0];
        int   ix = cand_i[tid][0];
#pragma unroll
        for (int r = 1; r < 4; ++r) {
            float ov = cand_v[tid][r];
            int   oi = cand_i[tid][r];
            if (ov > v || (ov == v && oi < ix)) { v = ov; ix = oi; }
        }
        bidx[tid] = ix;
    }
    __syncthreads();

    // ================= Epilogue: write one-hot rows =================
    const int NF4 = NC / 4;  // 250 float4 per row
    for (int q = tid; q < SPB * NF4; q += NTHR) {
        int row   = q / NF4;
        int c4    = q - row * NF4;
        int b     = bidx[row];
        int cbase = c4 * 4;
        float4 v;
        v.x = (cbase + 0 == b) ? 1.f : 0.f;
        v.y = (cbase + 1 == b) ? 1.f : 0.f;
        v.z = (cbase + 2 == b) ? 1.f : 0.f;
        v.w = (cbase + 3 == b) ? 1.f : 0.f;
        *reinterpret_cast<float4*>(out + (size_t)(s0 + row) * NC + cbase) = v;
    }
}

extern "C" void kernel_launch(void* const* d_in, const int* in_sizes, int n_in,
                              void* d_out, int out_size, void* d_ws, size_t ws_size,
                              hipStream_t stream) {
    const float* x     = (const float*)d_in[0];
    const float* W     = (const float*)d_in[1];
    const float* means = (const float*)d_in[2];
    float* out         = (float*)d_out;
    float* means4      = (float*)d_ws;   // 64*1024*4 floats = 1 MB (+1 row pad not needed: last prefetch never dereferenced past; loads stop at s=NSL-1 -> mp points at s=NSL.. wait, prefetch at s=NSL-1 reads mp for s=NSL)
    // NOTE: the prefetch at s=NSL-1 reads slice index NSL (one row past the
    // 1 MB table). d_ws is >= 2 MB in this harness; reads are in-bounds of the
    // workspace allocation and the values are discarded (bv copy unused).

    prep_means<<<(64 * NCP) / NTHR, NTHR, 0, stream>>>(means, means4);
    fused_cls_kernel<<<NS / SPB, NTHR, 0, stream>>>(x, W, means4, out);
}

// Round 6
// 137.588 us; speedup vs baseline: 2.3281x; 2.2128x over previous
//
#include <hip/hip_runtime.h>
#include <float.h>

// Problem constants (from reference setup_inputs)
#define NS   16384   // samples
#define K1   512     // d_in
#define F    256     // n_feat
#define NC   1000    // n_classes
#define SPB  32      // samples per block
#define NTHR 512     // 8 waves
#define NBLK (NS / SPB)

// f16 split-precision MFMA plan (see session notes):
//   value = hi + lo, hi = f16(v), lo = f16(v - hi)  => 2^-22 relative capture.
//   A*B ~= Ah*Bh + Ah*Bl + Al*Bh  (ll term ~2^-22 rel, dropped).
//   Pre-scale x*8, W*16, means*16: keeps lo terms in f16-normal range
//   (subnormal-flush-proof) and is argmax-invariant (positive scales).
// MFMA 16x16x32 f16 layouts (HW-verified m89/m91/m120):
//   A[m][k]: m=lane&15, k=(lane>>4)*8+j   (8 f16 per lane, k-contiguous)
//   B[k][n]: n=lane&15, k=(lane>>4)*8+j
//   C/D:     col=lane&15, row=(lane>>4)*4+reg
// Tie-break: reference argmin takes FIRST min => lowest class index wins.

typedef _Float16 half8 __attribute__((ext_vector_type(8)));
typedef float    float4v __attribute__((ext_vector_type(4)));

// Workspace layout in halves (_Float16):
//   Wh_swz: 256 tiles(ks*16+nt) * 64 lanes * 8 = 131072
//   Wl_swz: 131072
//   Mh_swz: 512 tiles(ks*64+gt) * 64 lanes * 8 = 262144
//   Ml_swz: 262144        total = 786432 halves = 1.5 MB
#define WH_OFF 0
#define WL_OFF 131072
#define MH_OFF 262144
#define ML_OFF (262144 + 262144)

// ---- prep: W[512][256] -> swizzled f16 hi/lo fragments (scale 16) ----
__global__ void prep_w(const float* __restrict__ W, _Float16* __restrict__ ws) {
    int g    = blockIdx.x * blockDim.x + threadIdx.x;  // 0..16383
    int lane = g & 63, tile = g >> 6;                  // tile = ks*16+nt
    int ks = tile >> 4, nt = tile & 15;
    int k0 = ks * 32 + (lane >> 4) * 8;
    int n  = nt * 16 + (lane & 15);
    _Float16 h[8], l[8];
#pragma unroll
    for (int j = 0; j < 8; ++j) {
        float v = W[(size_t)(k0 + j) * F + n] * 16.0f;
        _Float16 hi = (_Float16)v;
        h[j] = hi;
        l[j] = (_Float16)(v - (float)hi);
    }
    _Float16* dh = ws + WH_OFF + (size_t)g * 8;
    _Float16* dl = ws + WL_OFF + (size_t)g * 8;
#pragma unroll
    for (int j = 0; j < 8; ++j) { dh[j] = h[j]; dl[j] = l[j]; }
}

// ---- prep: means[1000][256] -> swizzled f16 hi/lo, zero-pad c>=NC, scale 16 ----
__global__ void prep_m(const float* __restrict__ means, _Float16* __restrict__ ws) {
    int g    = blockIdx.x * blockDim.x + threadIdx.x;  // 0..32767
    int lane = g & 63, tile = g >> 6;                  // tile = ks*64+gt
    int ks = tile >> 6, gt = tile & 63;
    int k0 = ks * 32 + (lane >> 4) * 8;
    int c  = gt * 16 + (lane & 15);
    _Float16 h[8], l[8];
#pragma unroll
    for (int j = 0; j < 8; ++j) {
        float v = (c < NC) ? means[(size_t)c * F + k0 + j] * 16.0f : 0.0f;
        _Float16 hi = (_Float16)v;
        h[j] = hi;
        l[j] = (_Float16)(v - (float)hi);
    }
    _Float16* dh = ws + MH_OFF + (size_t)g * 8;
    _Float16* dl = ws + ML_OFF + (size_t)g * 8;
#pragma unroll
    for (int j = 0; j < 8; ++j) { dh[j] = h[j]; dl[j] = l[j]; }
}

#define MFMA(a, b, c) __builtin_amdgcn_mfma_f32_16x16x32_f16((a), (b), (c), 0, 0, 0)

__attribute__((amdgpu_flat_work_group_size(NTHR, NTHR), amdgpu_waves_per_eu(2, 4)))
__global__ void fused_mfma(const float* __restrict__ x,
                           const _Float16* __restrict__ ws,
                           float* __restrict__ out) {
    // LDS ~47 KB -> 2 blocks/CU (VGPR/AGPR-limited), 16 waves/CU
    __shared__ _Float16 xsh[2][32][44];   // x chunk hi, ping-pong, padded stride
    __shared__ _Float16 xsl[2][32][44];   // x chunk lo
    __shared__ _Float16 fh[32][264];      // feats hi (scaled x128), padded stride
    __shared__ _Float16 fl[32][264];      // feats lo
    __shared__ float cand_v[32][8];
    __shared__ int   cand_i[32][8];
    __shared__ int   bidx[32];

    const int tid  = threadIdx.x;
    const int lane = tid & 63;
    const int w    = tid >> 6;    // wave 0..7
    const int quad = lane >> 4;   // 0..3
    const int cl   = lane & 15;
    const int s0   = blockIdx.x * SPB;

    // staging coords: 512 threads cover 32 rows x 32 cols (2 floats each)
    const int xrow = tid >> 4;          // 0..31
    const int xc   = (tid & 15) * 2;    // 0,2,..,30

    // ================= Phase 1: feats = (8x) @ (16W), f16-split MFMA ========
    float4v acc1[2][2];   // [p = n-subtile][mt]
#pragma unroll
    for (int p = 0; p < 2; ++p)
#pragma unroll
        for (int mt = 0; mt < 2; ++mt)
            acc1[p][mt] = (float4v){0.f, 0.f, 0.f, 0.f};

    float2 xv = *reinterpret_cast<const float2*>(x + (size_t)(s0 + xrow) * K1 + xc);

    for (int ks = 0; ks < 16; ++ks) {
        const int buf = ks & 1;
        {   // convert (scale x8) and stage
            float vx = xv.x * 8.0f, vy = xv.y * 8.0f;
            _Float16 hx = (_Float16)vx, hy = (_Float16)vy;
            xsh[buf][xrow][xc]     = hx;
            xsh[buf][xrow][xc + 1] = hy;
            xsl[buf][xrow][xc]     = (_Float16)(vx - (float)hx);
            xsl[buf][xrow][xc + 1] = (_Float16)(vy - (float)hy);
        }
        __syncthreads();
        if (ks < 15)
            xv = *reinterpret_cast<const float2*>(
                x + (size_t)(s0 + xrow) * K1 + (ks + 1) * 32 + xc);

        half8 ah[2], al[2];
#pragma unroll
        for (int mt = 0; mt < 2; ++mt) {
            ah[mt] = *reinterpret_cast<const half8*>(&xsh[buf][mt * 16 + cl][quad * 8]);
            al[mt] = *reinterpret_cast<const half8*>(&xsl[buf][mt * 16 + cl][quad * 8]);
        }
#pragma unroll
        for (int p = 0; p < 2; ++p) {
            const int tile = ks * 16 + (w * 2 + p);
            half8 bh = *reinterpret_cast<const half8*>(
                ws + WH_OFF + ((size_t)tile * 64 + lane) * 8);
            half8 bl = *reinterpret_cast<const half8*>(
                ws + WL_OFF + ((size_t)tile * 64 + lane) * 8);
#pragma unroll
            for (int mt = 0; mt < 2; ++mt) {
                acc1[p][mt] = MFMA(ah[mt], bh, acc1[p][mt]);
                acc1[p][mt] = MFMA(ah[mt], bl, acc1[p][mt]);
                acc1[p][mt] = MFMA(al[mt], bh, acc1[p][mt]);
            }
        }
        // no trailing barrier: next iter writes the other buffer
    }

    // park feats (scaled x128) into LDS as f16 hi/lo
#pragma unroll
    for (int p = 0; p < 2; ++p)
#pragma unroll
        for (int mt = 0; mt < 2; ++mt)
#pragma unroll
            for (int r = 0; r < 4; ++r) {
                int srow = mt * 16 + quad * 4 + r;
                int n    = (w * 2 + p) * 16 + cl;
                float v  = acc1[p][mt][r];
                _Float16 hi = (_Float16)v;
                fh[srow][n] = hi;
                fl[srow][n] = (_Float16)(v - (float)hi);
            }
    __syncthreads();

    // ========== Phase 2: scores = feats @ means.T, f16-split MFMA ==========
    // Wave w owns class tiles gt = w*8..w*8+7 (classes w*128..w*128+127),
    // for BOTH M-tiles => B-frag read once, 6 MFMAs per frag pair.
    float4v acc2[2][8];   // [mt][nt]
#pragma unroll
    for (int mt = 0; mt < 2; ++mt)
#pragma unroll
        for (int nt = 0; nt < 8; ++nt)
            acc2[mt][nt] = (float4v){0.f, 0.f, 0.f, 0.f};

    for (int ks = 0; ks < 8; ++ks) {
        half8 fah[2], fal[2];
#pragma unroll
        for (int mt = 0; mt < 2; ++mt) {
            fah[mt] = *reinterpret_cast<const half8*>(
                &fh[mt * 16 + cl][ks * 32 + quad * 8]);
            fal[mt] = *reinterpret_cast<const half8*>(
                &fl[mt * 16 + cl][ks * 32 + quad * 8]);
        }
#pragma unroll
        for (int nt = 0; nt < 8; ++nt) {
            const int tile = ks * 64 + (w * 8 + nt);
            half8 mh = *reinterpret_cast<const half8*>(
                ws + MH_OFF + ((size_t)tile * 64 + lane) * 8);
            half8 ml = *reinterpret_cast<const half8*>(
                ws + ML_OFF + ((size_t)tile * 64 + lane) * 8);
#pragma unroll
            for (int mt = 0; mt < 2; ++mt) {
                acc2[mt][nt] = MFMA(fah[mt], mh, acc2[mt][nt]);
                acc2[mt][nt] = MFMA(fah[mt], ml, acc2[mt][nt]);
                acc2[mt][nt] = MFMA(fal[mt], mh, acc2[mt][nt]);
            }
        }
    }

    // ---- argmax from C/D layout: row=quad*4+r, col=cl ----
#pragma unroll
    for (int mt = 0; mt < 2; ++mt)
#pragma unroll
        for (int r = 0; r < 4; ++r) {
            float v  = -FLT_MAX;
            int   ix = 0x7FFFFFFF;
#pragma unroll
            for (int nt = 0; nt < 8; ++nt) {          // ascending class order
                int c = (w * 8 + nt) * 16 + cl;
                if (c < NC) {
                    float sc = acc2[mt][nt][r];
                    if (sc > v) { v = sc; ix = c; }   // strict >: lowest wins
                }
            }
            // merge across the 16 lanes of this quad (they hold cl=0..15)
#pragma unroll
            for (int off = 1; off < 16; off <<= 1) {
                float ov = __shfl_xor(v, off, 64);
                int   oi = __shfl_xor(ix, off, 64);
                if (ov > v || (ov == v && oi < ix)) { v = ov; ix = oi; }
            }
            if (cl == 0) {
                int srow = mt * 16 + quad * 4 + r;
                cand_v[srow][w] = v;
                cand_i[srow][w] = ix;
            }
        }
    __syncthreads();

    if (tid < 32) {   // merge the 8 wave-candidates, ascending class ranges
        float v  = cand_v[tid][0];
        int   ix = cand_i[tid][0];
#pragma unroll
        for (int q = 1; q < 8; ++q) {
            float ov = cand_v[tid][q];
            int   oi = cand_i[tid][q];
            if (ov > v || (ov == v && oi < ix)) { v = ov; ix = oi; }
        }
        bidx[tid] = ix;
    }
    __syncthreads();

    // ================= Epilogue: write one-hot rows =================
    const int NF4 = NC / 4;  // 250 float4 per row
    for (int q = tid; q < SPB * NF4; q += NTHR) {
        int row   = q / NF4;
        int c4    = q - row * NF4;
        int b     = bidx[row];
        int cbase = c4 * 4;
        float4 v;
        v.x = (cbase + 0 == b) ? 1.f : 0.f;
        v.y = (cbase + 1 == b) ? 1.f : 0.f;
        v.z = (cbase + 2 == b) ? 1.f : 0.f;
        v.w = (cbase + 3 == b) ? 1.f : 0.f;
        *reinterpret_cast<float4*>(out + (size_t)(s0 + row) * NC + cbase) = v;
    }
}

extern "C" void kernel_launch(void* const* d_in, const int* in_sizes, int n_in,
                              void* d_out, int out_size, void* d_ws, size_t ws_size,
                              hipStream_t stream) {
    const float* x     = (const float*)d_in[0];
    const float* W     = (const float*)d_in[1];
    const float* means = (const float*)d_in[2];
    float* out         = (float*)d_out;
    _Float16* ws       = (_Float16*)d_ws;   // 1.5 MB of swizzled f16 fragments

    prep_w<<<64, 256, 0, stream>>>(W, ws);
    prep_m<<<128, 256, 0, stream>>>(means, ws);
    fused_mfma<<<NBLK, NTHR, 0, stream>>>(x, ws, out);
}